// Round 1
// baseline (386.110 us; speedup 1.0000x reference)
//
#include <hip/hip_runtime.h>
#include <math.h>

#define CC 2048   // channels (C)
#define DD 256    // reduced channels (D)
#define PP 4096   // HW = 64*64
#define NB 4      // batch

typedef float f32x16 __attribute__((ext_vector_type(16)));
typedef __bf16 bfrag __attribute__((ext_vector_type(8)));

#define AS1(p) ((const __attribute__((address_space(1))) void*)(p))
#define AS3(p) ((__attribute__((address_space(3))) void*)(p))

__device__ __forceinline__ unsigned short f2bf(float f) {
    unsigned int u = __float_as_uint(f);
    u = (u + 0x7fffu + ((u >> 16) & 1u)) >> 16;
    return (unsigned short)u;
}

// ---------------- fused: x transpose+cvt (z<NB) and w3 cvt (z==NB) ----------------
__global__ __launch_bounds__(256) void prep(const float* __restrict__ x, unsigned short* __restrict__ xT,
                                            const float* __restrict__ w3, unsigned short* __restrict__ w3b) {
    const int t = threadIdx.x;
    if (blockIdx.z == NB) {
        int bid = blockIdx.y * 64 + blockIdx.x;   // 0..2047
        int base = (bid * 256 + t) * 8;
#pragma unroll
        for (int j = 0; j < 2; ++j) {
            float4 v = *(const float4*)(w3 + base + j * 4);
            ushort4 r;
            r.x = f2bf(v.x); r.y = f2bf(v.y); r.z = f2bf(v.z); r.w = f2bf(v.w);
            *(ushort4*)(w3b + base + j * 4) = r;
        }
        return;
    }
    __shared__ float tile[64 * 64];
    const int n  = blockIdx.z;
    const int c0 = blockIdx.y * 64;
    const int p0 = blockIdx.x * 64;
    const float* xn = x + (size_t)n * CC * PP;
    {
        const int cl = t >> 4;
        const int g  = t & 15;
        const int pl = g * 4;
#pragma unroll
        for (int ps = 0; ps < 4; ++ps) {
            const int c = cl + ps * 16;
            float4 v = *(const float4*)(xn + (size_t)(c0 + c) * PP + p0 + pl);
            const int gs = g ^ (c >> 2);
            *(float4*)(tile + c * 64 + gs * 4) = v;
        }
    }
    __syncthreads();
    unsigned short* xTn = xT + (size_t)n * PP * CC;
    {
        const int pl2 = t >> 4;
        const int cq  = t & 15;
        const int c4  = cq * 4;
#pragma unroll
        for (int ps = 0; ps < 4; ++ps) {
            const int p  = pl2 + ps * 16;
            const int gs2 = (p >> 2) ^ cq;
            const int base = gs2 * 4 + (p & 3);
            ushort4 r;
            r.x = f2bf(tile[(c4 + 0) * 64 + base]);
            r.y = f2bf(tile[(c4 + 1) * 64 + base]);
            r.z = f2bf(tile[(c4 + 2) * 64 + base]);
            r.w = f2bf(tile[(c4 + 3) * 64 + base]);
            *(ushort4*)(xTn + (size_t)(p0 + p) * CC + c0 + c4) = r;
        }
    }
}

// ---------------- assembly = relu(w3 . x + b3) ----------------
// 256x256 tile, BK=64, 8 waves (2M x 4N), wave tile 128x64 via 4x2 of
// mfma_f32_32x32x16_bf16. 8-phase/2-Ktile schedule (T3+T4+T5): per phase
// {ds_read subtile | issue 1 half-tile global_load_lds -> s_barrier ->
// lgkmcnt(0) -> setprio(1) -> 8 MFMA -> setprio(0) -> s_barrier}; counted
// vmcnt(4) once per K-tile (never 0 in main loop). LDS 128KB: 2 buffers x
// (A:2 halves 128x64 + B:2 halves 128x64) bf16, chunk-XOR swizzled via the
// pre-swizzled GLOBAL source (slot s of row r holds k-chunk s^(r&7)).
__global__ __launch_bounds__(512, 2) void gemm_assembly(
    const unsigned short* __restrict__ w3b,
    const unsigned short* __restrict__ xT,
    const float* __restrict__ b3,
    float* __restrict__ out)
{
    // layout (bytes): A: buf*32768 + half*16384 + row*128 ; B: +65536 same
    __shared__ __align__(16) char sm[131072];

    const int t    = threadIdx.x;
    const int wave = t >> 6;
    const int lane = t & 63;
    const int l31  = lane & 31;
    const int lh   = lane >> 5;
    const int swz  = lane & 7;

    // XCD-aware bijective swizzle within the 128-wg z-plane (128 % 8 == 0):
    // XCD x owns one full M-row of tiles -> shared A panel in its L2.
    const int flat = blockIdx.x + (blockIdx.y << 4);
    const int sf   = ((flat & 7) << 4) | (flat >> 3);
    const int p0   = (sf & 15) << 8;
    const int m0   = (sf >> 4) << 8;
    const int nb   = blockIdx.z;

    // staging: thread t covers row rA (+64 for 2nd issue), global chunk g
    const int rA = t >> 3;              // 0..63
    const int g  = (t & 7) ^ (rA & 7);
    const unsigned short* Ag = w3b + (size_t)(m0 + rA) * CC + g * 8;
    const unsigned short* Bg = xT + (size_t)nb * PP * CC + (size_t)(p0 + rA) * CC + g * 8;
    const int ldsw = wave << 10;        // wave*1024 (HW adds lane*16)

    // ds_read bases: wave's A half = wave>>2 ; B half = (wave&3)>>1
    const char* Abase = sm + ((wave >> 2) << 14) + l31 * 128;
    const char* Bbase = sm + 65536 + (((wave & 3) >> 1) << 14) + ((((wave & 1) << 6) + l31) * 128);

    // swizzled chunk byte offsets per k-slice (row&7 == lane&7 for all frags)
    const int ck0 = ((0 + lh) ^ swz) << 4;
    const int ck1 = ((2 + lh) ^ swz) << 4;
    const int ck2 = ((4 + lh) ^ swz) << 4;
    const int ck3 = ((6 + lh) ^ swz) << 4;

    f32x16 c00 = {}, c10 = {}, c20 = {}, c30 = {};
    f32x16 c01 = {}, c11 = {}, c21 = {}, c31 = {};
    bfrag a0_0, a0_1, a0_2, a0_3, a1_0, a1_1, a1_2, a1_3;
    bfrag b0_0, b0_1, b0_2, b0_3, b1_0, b1_1, b1_2, b1_3;

#define STG(SB, DO, kt, h) do { \
    const unsigned short* _s = (SB) + (size_t)(h) * 128 * CC + (size_t)(kt) * 64; \
    char* _d = sm + (DO) + (((kt) & 1) << 15) + ((h) << 14) + ldsw; \
    __builtin_amdgcn_global_load_lds(AS1(_s), AS3(_d), 16, 0, 0); \
    __builtin_amdgcn_global_load_lds(AS1(_s + 64 * CC), AS3(_d + 8192), 16, 0, 0); \
} while (0)

#define LDA(dst, P, mi, ck) dst = *(const bfrag*)(Abase + ((P) << 15) + ((mi) << 12) + (ck))
#define LDB(dst, P, ni, ck) dst = *(const bfrag*)(Bbase + ((P) << 15) + ((ni) << 12) + (ck))
#define MM(acc, a, b) acc = __builtin_amdgcn_mfma_f32_32x32x16_bf16(a, b, acc, 0, 0, 0)
#define BARR __builtin_amdgcn_s_barrier()
#define LG0 do { asm volatile("s_waitcnt lgkmcnt(0)" ::: "memory"); __builtin_amdgcn_sched_barrier(0); } while (0)
#define PRI(x) __builtin_amdgcn_s_setprio(x)

// One K-tile = 4 phases. Quadrant order (mh0,n0)(mh0,n1)(mh1,n1)(mh1,n0):
// B halves last LDS-read at p2 -> issue (kt+2)B0@p3, B1@p4 (same buffer);
// A halves last LDS-read at p3 -> issue (kt+1)A0@p1, A1@p2 (other buffer).
// vmcnt(4) at p4 leaves only the two newest B half-tiles in flight.
#define TILE(P, kt, IA, IB, VMS, VMZ) do { \
    /* phase 1: (mh0,nh0) — 12 ds_reads */ \
    LDA(a0_0,P,0,ck0); LDA(a0_1,P,0,ck1); LDA(a0_2,P,0,ck2); LDA(a0_3,P,0,ck3); \
    LDA(a1_0,P,1,ck0); LDA(a1_1,P,1,ck1); LDA(a1_2,P,1,ck2); LDA(a1_3,P,1,ck3); \
    LDB(b0_0,P,0,ck0); LDB(b0_1,P,0,ck1); LDB(b0_2,P,0,ck2); LDB(b0_3,P,0,ck3); \
    if (IA) STG(Ag, 0, (kt) + 1, 0); \
    asm volatile("s_waitcnt lgkmcnt(8)" ::: "memory"); \
    BARR; LG0; PRI(1); \
    MM(c00, a0_0, b0_0); MM(c10, a1_0, b0_0); \
    MM(c00, a0_1, b0_1); MM(c10, a1_1, b0_1); \
    MM(c00, a0_2, b0_2); MM(c10, a1_2, b0_2); \
    MM(c00, a0_3, b0_3); MM(c10, a1_3, b0_3); \
    PRI(0); BARR; \
    /* phase 2: (mh0,nh1) — 4 ds_reads */ \
    LDB(b1_0,P,1,ck0); LDB(b1_1,P,1,ck1); LDB(b1_2,P,1,ck2); LDB(b1_3,P,1,ck3); \
    if (IA) STG(Ag, 0, (kt) + 1, 1); \
    BARR; LG0; PRI(1); \
    MM(c01, a0_0, b1_0); MM(c11, a1_0, b1_0); \
    MM(c01, a0_1, b1_1); MM(c11, a1_1, b1_1); \
    MM(c01, a0_2, b1_2); MM(c11, a1_2, b1_2); \
    MM(c01, a0_3, b1_3); MM(c11, a1_3, b1_3); \
    PRI(0); BARR; \
    /* phase 3: (mh1,nh1) — 8 ds_reads, A regs -> frags 2,3 */ \
    LDA(a0_0,P,2,ck0); LDA(a0_1,P,2,ck1); LDA(a0_2,P,2,ck2); LDA(a0_3,P,2,ck3); \
    LDA(a1_0,P,3,ck0); LDA(a1_1,P,3,ck1); LDA(a1_2,P,3,ck2); LDA(a1_3,P,3,ck3); \
    if (IB) STG(Bg, 65536, (kt) + 2, 0); \
    BARR; LG0; PRI(1); \
    MM(c21, a0_0, b1_0); MM(c31, a1_0, b1_0); \
    MM(c21, a0_1, b1_1); MM(c31, a1_1, b1_1); \
    MM(c21, a0_2, b1_2); MM(c31, a1_2, b1_2); \
    MM(c21, a0_3, b1_3); MM(c31, a1_3, b1_3); \
    PRI(0); BARR; \
    /* phase 4: (mh1,nh0) — all from regs */ \
    if (IB) STG(Bg, 65536, (kt) + 2, 1); \
    BARR; PRI(1); \
    MM(c20, a0_0, b0_0); MM(c30, a1_0, b0_0); \
    MM(c20, a0_1, b0_1); MM(c30, a1_1, b0_1); \
    MM(c20, a0_2, b0_2); MM(c30, a1_2, b0_2); \
    MM(c20, a0_3, b0_3); MM(c30, a1_3, b0_3); \
    PRI(0); \
    if (VMS) asm volatile("s_waitcnt vmcnt(4)" ::: "memory"); \
    if (VMZ) asm volatile("s_waitcnt vmcnt(0)" ::: "memory"); \
    BARR; \
} while (0)

    // prologue: tile 0 (all 4 halves) + tile 1 (B halves); tile 1 A halves
    // arrive at t0.p1/p2; tile 2 B halves at t0.p3/p4.
    STG(Ag, 0, 0, 0); STG(Ag, 0, 0, 1);
    STG(Bg, 65536, 0, 0); STG(Bg, 65536, 0, 1);
    STG(Bg, 65536, 1, 0); STG(Bg, 65536, 1, 1);
    asm volatile("s_waitcnt vmcnt(4)" ::: "memory");
    BARR;

#pragma unroll 1
    for (int kt = 0; kt < 30; kt += 2) {
        TILE(0, kt,     1, 1, 1, 0);
        TILE(1, kt + 1, 1, 1, 1, 0);
    }
    TILE(0, 30, 1, 0, 0, 1);   // issues (31)A0/A1, drains with vmcnt(0)
    TILE(1, 31, 0, 0, 0, 0);   // pure compute

#undef TILE
#undef STG
#undef LDA
#undef LDB
#undef MM
#undef BARR
#undef LG0
#undef PRI

    // epilogue: C/D layout (32x32): row=(reg&3)+8*(reg>>2)+4*(lane>>5), col=lane&31
    const int wr = (wave >> 2) << 7;
    const int wc = (wave & 3) << 6;
    float* outn = out + (size_t)nb * CC * PP + p0 + wc + l31;
#pragma unroll
    for (int mi = 0; mi < 4; ++mi) {
        f32x16 v0 = (mi == 0) ? c00 : (mi == 1) ? c10 : (mi == 2) ? c20 : c30;
        f32x16 v1 = (mi == 0) ? c01 : (mi == 1) ? c11 : (mi == 2) ? c21 : c31;
#pragma unroll
        for (int r = 0; r < 16; ++r) {
            const int rowl = (r & 3) + 8 * (r >> 2) + 4 * lh;
            const int o = m0 + wr + mi * 32 + rowl;
            const float bias = b3[o];
            float* orow = outn + (size_t)o * PP;
            float x0 = v0[r] + bias;
            float x1 = v1[r] + bias;
            orow[0]  = x0 > 0.f ? x0 : 0.f;
            orow[32] = x1 > 0.f ? x1 : 0.f;
        }
    }
}

// ---------------- guarded attention fallback (alpha != 0 only) ----------------
__global__ void fb_e12(const float* __restrict__ x,
                       const float* __restrict__ w1, const float* __restrict__ b1,
                       const float* __restrict__ w2, const float* __restrict__ b2,
                       const float* __restrict__ alpha,
                       float* __restrict__ e1, float* __restrict__ e2) {
    if (alpha[0] == 0.f) return;
    const size_t total = (size_t)NB * DD * PP;
    for (size_t idx = (size_t)blockIdx.x * blockDim.x + threadIdx.x; idx < total;
         idx += (size_t)gridDim.x * blockDim.x) {
        int p = (int)(idx % PP);
        size_t nd = idx / PP;
        int d = (int)(nd % DD);
        int n = (int)(nd / DD);
        const float* xn = x + (size_t)n * CC * PP + p;
        float s1 = b1[d], s2 = b2[d];
        for (int c = 0; c < CC; ++c) {
            float xv = xn[(size_t)c * PP];
            s1 += w1[(size_t)d * CC + c] * xv;
            s2 += w2[(size_t)d * CC + c] * xv;
        }
        e1[idx] = fmaxf(s1, 0.f);
        e2[idx] = fmaxf(s2, 0.f);
    }
}

__global__ void fb_attn(const float* __restrict__ x,
                        const float* __restrict__ e1, const float* __restrict__ e2,
                        const float* __restrict__ alpha,
                        float* __restrict__ out) {
    const float a = alpha[0];
    if (a == 0.f) return;   // uniform early-exit (no barrier crossed)
    __shared__ float s[PP];
    __shared__ float e1i[DD];
    __shared__ float red[256];
    const int t = threadIdx.x;
    for (int ii = blockIdx.x; ii < NB * PP; ii += gridDim.x) {
        const int n = ii >> 12;
        const int i = ii & (PP - 1);
        const float* e1n = e1 + (size_t)n * DD * PP;
        const float* e2n = e2 + (size_t)n * DD * PP;
        if (t < DD) e1i[t] = e1n[(size_t)t * PP + i];
        __syncthreads();
        for (int j = t; j < PP; j += 256) {
            float acc = 0.f;
            for (int d = 0; d < DD; ++d) acc += e1i[d] * e2n[(size_t)d * PP + j];
            s[j] = acc;
        }
        __syncthreads();
        float m = -INFINITY;
        for (int j = t; j < PP; j += 256) m = fmaxf(m, s[j]);
        red[t] = m; __syncthreads();
        for (int o = 128; o > 0; o >>= 1) { if (t < o) red[t] = fmaxf(red[t], red[t + o]); __syncthreads(); }
        m = red[0]; __syncthreads();
        float l = 0.f;
        for (int j = t; j < PP; j += 256) { float e = __expf(s[j] - m); s[j] = e; l += e; }
        red[t] = l; __syncthreads();
        for (int o = 128; o > 0; o >>= 1) { if (t < o) red[t] += red[t + o]; __syncthreads(); }
        l = red[0]; __syncthreads();
        const float inv = a / l;
        const float* xn = x + (size_t)n * CC * PP;
        float* on = out + (size_t)n * CC * PP;
        for (int c = t; c < CC; c += 256) {
            const float* xr = xn + (size_t)c * PP;
            float acc = 0.f;
            for (int j = 0; j < PP; ++j) acc += s[j] * xr[j];
            on[(size_t)c * PP + i] += inv * acc;
        }
        __syncthreads();
    }
}

extern "C" void kernel_launch(void* const* d_in, const int* in_sizes, int n_in,
                              void* d_out, int out_size, void* d_ws, size_t ws_size,
                              hipStream_t stream) {
    (void)in_sizes; (void)n_in; (void)out_size; (void)ws_size;
    const float* x     = (const float*)d_in[0];
    const float* w1    = (const float*)d_in[1];
    const float* b1    = (const float*)d_in[2];
    const float* w2    = (const float*)d_in[3];
    const float* b2    = (const float*)d_in[4];
    const float* w3    = (const float*)d_in[5];
    const float* b3    = (const float*)d_in[6];
    const float* alpha = (const float*)d_in[7];
    float* out = (float*)d_out;

    unsigned short* xT  = (unsigned short*)d_ws;
    unsigned short* w3b = (unsigned short*)((char*)d_ws + (size_t)NB * PP * CC * 2);
    float* e1 = (float*)d_ws;
    float* e2 = e1 + (size_t)NB * DD * PP;

    prep<<<dim3(PP / 64, CC / 64, NB + 1), dim3(256), 0, stream>>>(x, xT, w3, w3b);
    gemm_assembly<<<dim3(PP / 256, CC / 256, NB), dim3(512), 0, stream>>>(w3b, xT, b3, out);
    fb_e12<<<dim3(512), dim3(256), 0, stream>>>(x, w1, b1, w2, b2, alpha, e1, e2);
    fb_attn<<<dim3(1024), dim3(256), 0, stream>>>(x, e1, e2, alpha, out);
}

// Round 2
// 375.820 us; speedup vs baseline: 1.0274x; 1.0274x over previous
//
#include <hip/hip_runtime.h>
#include <math.h>

#define CC 2048   // channels (C)
#define DD 256    // reduced channels (D)
#define PP 4096   // HW = 64*64
#define NB 4      // batch

typedef float f32x16 __attribute__((ext_vector_type(16)));
typedef __bf16 bfrag __attribute__((ext_vector_type(8)));

#define AS1(p) ((const __attribute__((address_space(1))) void*)(p))
#define AS3(p) ((__attribute__((address_space(3))) void*)(p))

__device__ __forceinline__ unsigned short f2bf(float f) {
    unsigned int u = __float_as_uint(f);
    u = (u + 0x7fffu + ((u >> 16) & 1u)) >> 16;
    return (unsigned short)u;
}

// ---------------- fused: x transpose+cvt (z<NB) and w3 cvt (z==NB) ----------------
__global__ __launch_bounds__(256) void prep(const float* __restrict__ x, unsigned short* __restrict__ xT,
                                            const float* __restrict__ w3, unsigned short* __restrict__ w3b) {
    const int t = threadIdx.x;
    if (blockIdx.z == NB) {
        int bid = blockIdx.y * 64 + blockIdx.x;   // 0..2047
        int base = (bid * 256 + t) * 8;
#pragma unroll
        for (int j = 0; j < 2; ++j) {
            float4 v = *(const float4*)(w3 + base + j * 4);
            ushort4 r;
            r.x = f2bf(v.x); r.y = f2bf(v.y); r.z = f2bf(v.z); r.w = f2bf(v.w);
            *(ushort4*)(w3b + base + j * 4) = r;
        }
        return;
    }
    __shared__ float tile[64 * 64];
    const int n  = blockIdx.z;
    const int c0 = blockIdx.y * 64;
    const int p0 = blockIdx.x * 64;
    const float* xn = x + (size_t)n * CC * PP;
    {
        const int cl = t >> 4;
        const int g  = t & 15;
        const int pl = g * 4;
#pragma unroll
        for (int ps = 0; ps < 4; ++ps) {
            const int c = cl + ps * 16;
            float4 v = *(const float4*)(xn + (size_t)(c0 + c) * PP + p0 + pl);
            const int gs = g ^ (c >> 2);
            *(float4*)(tile + c * 64 + gs * 4) = v;
        }
    }
    __syncthreads();
    unsigned short* xTn = xT + (size_t)n * PP * CC;
    {
        const int pl2 = t >> 4;
        const int cq  = t & 15;
        const int c4  = cq * 4;
#pragma unroll
        for (int ps = 0; ps < 4; ++ps) {
            const int p  = pl2 + ps * 16;
            const int gs2 = (p >> 2) ^ cq;
            const int base = gs2 * 4 + (p & 3);
            ushort4 r;
            r.x = f2bf(tile[(c4 + 0) * 64 + base]);
            r.y = f2bf(tile[(c4 + 1) * 64 + base]);
            r.z = f2bf(tile[(c4 + 2) * 64 + base]);
            r.w = f2bf(tile[(c4 + 3) * 64 + base]);
            *(ushort4*)(xTn + (size_t)(p0 + p) * CC + c0 + c4) = r;
        }
    }
}

// ---------------- assembly = relu(w3 . x + b3) ----------------
// 256x256 tile, BK=64, 8 waves (2M x 4N), wave tile 128x64 via 4x2 of
// mfma_f32_32x32x16_bf16. Software-pipelined K-tile: all 24 ds_reads issued
// up front in 3 pinned groups (A01+B0 | B1 | A23), MFMA quadrants run behind
// counted lgkmcnt(12)/(8)/(0) so LDS service overlaps MFMA issue. Only TWO
// barriers per K-tile: mid (before STG-B overwrites the live B region) and
// end (dbuf handoff). Counted vmcnt(4) once per tile (A prefetch +1, B +2).
// NO XCD swizzle: natural blockIdx order gives each XCD 2 B-panels (the big
// operand) -> B L2-resident, FETCH ~= compulsory (round-0 evidence: 99 MB
// natural vs 270 MB with the A-centric swizzle).
__global__ __launch_bounds__(512, 2) void gemm_assembly(
    const unsigned short* __restrict__ w3b,
    const unsigned short* __restrict__ xT,
    const float* __restrict__ b3,
    float* __restrict__ out)
{
    // layout (bytes): A: buf*32768 + half*16384 + row*128 ; B: +65536 same
    __shared__ __align__(16) char sm[131072];

    const int t    = threadIdx.x;
    const int wave = t >> 6;
    const int lane = t & 63;
    const int l31  = lane & 31;
    const int lh   = lane >> 5;
    const int swz  = lane & 7;

    const int p0 = blockIdx.x << 8;
    const int m0 = blockIdx.y << 8;
    const int nb = blockIdx.z;

    // staging: thread t covers row rA (+64 for 2nd issue), global chunk g
    const int rA = t >> 3;              // 0..63
    const int g  = (t & 7) ^ (rA & 7);
    const unsigned short* Ag = w3b + (size_t)(m0 + rA) * CC + g * 8;
    const unsigned short* Bg = xT + (size_t)nb * PP * CC + (size_t)(p0 + rA) * CC + g * 8;
    const int ldsw = wave << 10;        // wave*1024 (HW adds lane*16)

    // ds_read bases: wave's A half = wave>>2 ; B half = (wave&3)>>1
    const char* Abase = sm + ((wave >> 2) << 14) + l31 * 128;
    const char* Bbase = sm + 65536 + (((wave & 3) >> 1) << 14) + ((((wave & 1) << 6) + l31) * 128);

    // swizzled chunk byte offsets per k-slice (row&7 == lane&7 for all frags)
    const int ck0 = ((0 + lh) ^ swz) << 4;
    const int ck1 = ((2 + lh) ^ swz) << 4;
    const int ck2 = ((4 + lh) ^ swz) << 4;
    const int ck3 = ((6 + lh) ^ swz) << 4;

    f32x16 c00 = {}, c10 = {}, c20 = {}, c30 = {};
    f32x16 c01 = {}, c11 = {}, c21 = {}, c31 = {};
    bfrag aA0_0, aA0_1, aA0_2, aA0_3;
    bfrag aA1_0, aA1_1, aA1_2, aA1_3;
    bfrag aA2_0, aA2_1, aA2_2, aA2_3;
    bfrag aA3_0, aA3_1, aA3_2, aA3_3;
    bfrag b0_0, b0_1, b0_2, b0_3, b1_0, b1_1, b1_2, b1_3;

#define STG(SB, DO, kt, h) do { \
    const unsigned short* _s = (SB) + (size_t)(h) * 128 * CC + (size_t)(kt) * 64; \
    char* _d = sm + (DO) + (((kt) & 1) << 15) + ((h) << 14) + ldsw; \
    __builtin_amdgcn_global_load_lds(AS1(_s), AS3(_d), 16, 0, 0); \
    __builtin_amdgcn_global_load_lds(AS1(_s + 64 * CC), AS3(_d + 8192), 16, 0, 0); \
} while (0)

#define LDA(dst, P, mi, ck) dst = *(const bfrag*)(Abase + ((P) << 15) + ((mi) << 12) + (ck))
#define LDB(dst, P, ni, ck) dst = *(const bfrag*)(Bbase + ((P) << 15) + ((ni) << 12) + (ck))
#define MM(acc, a, b) acc = __builtin_amdgcn_mfma_f32_32x32x16_bf16(a, b, acc, 0, 0, 0)
#define BARR __builtin_amdgcn_s_barrier()
#define SB0  __builtin_amdgcn_sched_barrier(0)
#define PRI(x) __builtin_amdgcn_s_setprio(x)

// One K-tile. Entry invariant: buffer P holds A(kt),B(kt); exactly B(kt+1)'s
// 4 loads outstanding. Reads front-loaded; quadrants behind counted lgkmcnt.
// Mid-barrier: all waves' B(kt) LDS reads retired (lgkm<=8 passed) before any
// STG-B(kt+2) write can land in the same region. vmcnt(4) at tile end retires
// A(kt+1)+B(kt+1), leaving B(kt+2) in flight.
#define TILE(P, kt, IA, IB, VM4, VM0, EB) do { \
    SB0; \
    /* G1: A mi0,mi1 + B n0 — 12 reads */ \
    LDA(aA0_0,P,0,ck0); LDA(aA0_1,P,0,ck1); LDA(aA0_2,P,0,ck2); LDA(aA0_3,P,0,ck3); \
    LDA(aA1_0,P,1,ck0); LDA(aA1_1,P,1,ck1); LDA(aA1_2,P,1,ck2); LDA(aA1_3,P,1,ck3); \
    LDB(b0_0,P,0,ck0);  LDB(b0_1,P,0,ck1);  LDB(b0_2,P,0,ck2);  LDB(b0_3,P,0,ck3); \
    SB0; \
    if (IA) STG(Ag, 0, (kt) + 1, 0); \
    /* G2: B n1 — 4 reads */ \
    LDB(b1_0,P,1,ck0);  LDB(b1_1,P,1,ck1);  LDB(b1_2,P,1,ck2);  LDB(b1_3,P,1,ck3); \
    SB0; \
    if (IA) STG(Ag, 0, (kt) + 1, 1); \
    /* G3: A mi2,mi3 — 8 reads */ \
    LDA(aA2_0,P,2,ck0); LDA(aA2_1,P,2,ck1); LDA(aA2_2,P,2,ck2); LDA(aA2_3,P,2,ck3); \
    LDA(aA3_0,P,3,ck0); LDA(aA3_1,P,3,ck1); LDA(aA3_2,P,3,ck2); LDA(aA3_3,P,3,ck3); \
    SB0; \
    /* quadrant 1: (mi01, n0) — needs G1 only; G2+G3 (12) still in flight */ \
    asm volatile("s_waitcnt lgkmcnt(12)" ::: "memory"); SB0; \
    PRI(1); \
    MM(c00, aA0_0, b0_0); MM(c10, aA1_0, b0_0); \
    MM(c00, aA0_1, b0_1); MM(c10, aA1_1, b0_1); \
    MM(c00, aA0_2, b0_2); MM(c10, aA1_2, b0_2); \
    MM(c00, aA0_3, b0_3); MM(c10, aA1_3, b0_3); \
    PRI(0); \
    /* quadrant 2: (mi01, n1) — needs G2; G3 (8) still in flight */ \
    asm volatile("s_waitcnt lgkmcnt(8)" ::: "memory"); SB0; \
    PRI(1); \
    MM(c01, aA0_0, b1_0); MM(c11, aA1_0, b1_0); \
    MM(c01, aA0_1, b1_1); MM(c11, aA1_1, b1_1); \
    MM(c01, aA0_2, b1_2); MM(c11, aA1_2, b1_2); \
    MM(c01, aA0_3, b1_3); MM(c11, aA1_3, b1_3); \
    PRI(0); \
    BARR; SB0; \
    if (IB) STG(Bg, 65536, (kt) + 2, 0); \
    /* quadrant 3: (mi23, n1) — needs G3 */ \
    asm volatile("s_waitcnt lgkmcnt(0)" ::: "memory"); SB0; \
    PRI(1); \
    MM(c21, aA2_0, b1_0); MM(c31, aA3_0, b1_0); \
    MM(c21, aA2_1, b1_1); MM(c31, aA3_1, b1_1); \
    MM(c21, aA2_2, b1_2); MM(c31, aA3_2, b1_2); \
    MM(c21, aA2_3, b1_3); MM(c31, aA3_3, b1_3); \
    PRI(0); \
    if (IB) STG(Bg, 65536, (kt) + 2, 1); \
    /* quadrant 4: (mi23, n0) — all regs */ \
    PRI(1); \
    MM(c20, aA2_0, b0_0); MM(c30, aA3_0, b0_0); \
    MM(c20, aA2_1, b0_1); MM(c30, aA3_1, b0_1); \
    MM(c20, aA2_2, b0_2); MM(c30, aA3_2, b0_2); \
    MM(c20, aA2_3, b0_3); MM(c30, aA3_3, b0_3); \
    PRI(0); \
    if (VM4) asm volatile("s_waitcnt vmcnt(4)" ::: "memory"); \
    if (VM0) asm volatile("s_waitcnt vmcnt(0)" ::: "memory"); \
    if (EB) BARR; \
} while (0)

    // prologue: A(0),B(0) -> buf0; B(1) -> buf1. vmcnt(4) retires A(0)+B(0),
    // leaves B(1)'s 4 ops = loop entry invariant.
    STG(Ag, 0, 0, 0); STG(Ag, 0, 0, 1);
    STG(Bg, 65536, 0, 0); STG(Bg, 65536, 0, 1);
    STG(Bg, 65536, 1, 0); STG(Bg, 65536, 1, 1);
    asm volatile("s_waitcnt vmcnt(4)" ::: "memory");
    BARR;

#pragma unroll 1
    for (int kt = 0; kt < 30; kt += 2) {
        TILE(0, kt,     1, 1, 1, 0, 1);
        TILE(1, kt + 1, 1, (kt + 1 < 30), 1, 0, 1);
    }
    TILE(0, 30, 1, 0, 0, 1, 1);   // stages A(31); drains with vmcnt(0)
    TILE(1, 31, 0, 0, 0, 0, 0);   // pure compute

#undef TILE
#undef STG
#undef LDA
#undef LDB
#undef MM
#undef BARR
#undef SB0
#undef PRI

    // epilogue: C/D layout (32x32): row=(reg&3)+8*(reg>>2)+4*(lane>>5), col=lane&31
    const int wr = (wave >> 2) << 7;
    const int wc = (wave & 3) << 6;
    float* outn = out + (size_t)nb * CC * PP + p0 + wc + l31;
#pragma unroll
    for (int mi = 0; mi < 4; ++mi) {
        f32x16 v0 = (mi == 0) ? c00 : (mi == 1) ? c10 : (mi == 2) ? c20 : c30;
        f32x16 v1 = (mi == 0) ? c01 : (mi == 1) ? c11 : (mi == 2) ? c21 : c31;
#pragma unroll
        for (int r = 0; r < 16; ++r) {
            const int rowl = (r & 3) + 8 * (r >> 2) + 4 * lh;
            const int o = m0 + wr + mi * 32 + rowl;
            const float bias = b3[o];
            float* orow = outn + (size_t)o * PP;
            float x0 = v0[r] + bias;
            float x1 = v1[r] + bias;
            orow[0]  = x0 > 0.f ? x0 : 0.f;
            orow[32] = x1 > 0.f ? x1 : 0.f;
        }
    }
}

// ---------------- guarded attention fallback (alpha != 0 only) ----------------
__global__ void fb_e12(const float* __restrict__ x,
                       const float* __restrict__ w1, const float* __restrict__ b1,
                       const float* __restrict__ w2, const float* __restrict__ b2,
                       const float* __restrict__ alpha,
                       float* __restrict__ e1, float* __restrict__ e2) {
    if (alpha[0] == 0.f) return;
    const size_t total = (size_t)NB * DD * PP;
    for (size_t idx = (size_t)blockIdx.x * blockDim.x + threadIdx.x; idx < total;
         idx += (size_t)gridDim.x * blockDim.x) {
        int p = (int)(idx % PP);
        size_t nd = idx / PP;
        int d = (int)(nd % DD);
        int n = (int)(nd / DD);
        const float* xn = x + (size_t)n * CC * PP + p;
        float s1 = b1[d], s2 = b2[d];
        for (int c = 0; c < CC; ++c) {
            float xv = xn[(size_t)c * PP];
            s1 += w1[(size_t)d * CC + c] * xv;
            s2 += w2[(size_t)d * CC + c] * xv;
        }
        e1[idx] = fmaxf(s1, 0.f);
        e2[idx] = fmaxf(s2, 0.f);
    }
}

__global__ void fb_attn(const float* __restrict__ x,
                        const float* __restrict__ e1, const float* __restrict__ e2,
                        const float* __restrict__ alpha,
                        float* __restrict__ out) {
    const float a = alpha[0];
    if (a == 0.f) return;   // uniform early-exit (no barrier crossed)
    __shared__ float s[PP];
    __shared__ float e1i[DD];
    __shared__ float red[256];
    const int t = threadIdx.x;
    for (int ii = blockIdx.x; ii < NB * PP; ii += gridDim.x) {
        const int n = ii >> 12;
        const int i = ii & (PP - 1);
        const float* e1n = e1 + (size_t)n * DD * PP;
        const float* e2n = e2 + (size_t)n * DD * PP;
        if (t < DD) e1i[t] = e1n[(size_t)t * PP + i];
        __syncthreads();
        for (int j = t; j < PP; j += 256) {
            float acc = 0.f;
            for (int d = 0; d < DD; ++d) acc += e1i[d] * e2n[(size_t)d * PP + j];
            s[j] = acc;
        }
        __syncthreads();
        float m = -INFINITY;
        for (int j = t; j < PP; j += 256) m = fmaxf(m, s[j]);
        red[t] = m; __syncthreads();
        for (int o = 128; o > 0; o >>= 1) { if (t < o) red[t] = fmaxf(red[t], red[t + o]); __syncthreads(); }
        m = red[0]; __syncthreads();
        float l = 0.f;
        for (int j = t; j < PP; j += 256) { float e = __expf(s[j] - m); s[j] = e; l += e; }
        red[t] = l; __syncthreads();
        for (int o = 128; o > 0; o >>= 1) { if (t < o) red[t] += red[t + o]; __syncthreads(); }
        l = red[0]; __syncthreads();
        const float inv = a / l;
        const float* xn = x + (size_t)n * CC * PP;
        float* on = out + (size_t)n * CC * PP;
        for (int c = t; c < CC; c += 256) {
            const float* xr = xn + (size_t)c * PP;
            float acc = 0.f;
            for (int j = 0; j < PP; ++j) acc += s[j] * xr[j];
            on[(size_t)c * PP + i] += inv * acc;
        }
        __syncthreads();
    }
}

extern "C" void kernel_launch(void* const* d_in, const int* in_sizes, int n_in,
                              void* d_out, int out_size, void* d_ws, size_t ws_size,
                              hipStream_t stream) {
    (void)in_sizes; (void)n_in; (void)out_size; (void)ws_size;
    const float* x     = (const float*)d_in[0];
    const float* w1    = (const float*)d_in[1];
    const float* b1    = (const float*)d_in[2];
    const float* w2    = (const float*)d_in[3];
    const float* b2    = (const float*)d_in[4];
    const float* w3    = (const float*)d_in[5];
    const float* b3    = (const float*)d_in[6];
    const float* alpha = (const float*)d_in[7];
    float* out = (float*)d_out;

    unsigned short* xT  = (unsigned short*)d_ws;
    unsigned short* w3b = (unsigned short*)((char*)d_ws + (size_t)NB * PP * CC * 2);
    float* e1 = (float*)d_ws;
    float* e2 = e1 + (size_t)NB * DD * PP;

    prep<<<dim3(PP / 64, CC / 64, NB + 1), dim3(256), 0, stream>>>(x, xT, w3, w3b);
    gemm_assembly<<<dim3(PP / 256, CC / 256, NB), dim3(512), 0, stream>>>(w3b, xT, b3, out);
    fb_e12<<<dim3(512), dim3(256), 0, stream>>>(x, w1, b1, w2, b2, alpha, e1, e2);
    fb_attn<<<dim3(1024), dim3(256), 0, stream>>>(x, e1, e2, alpha, out);
}

// Round 3
// 361.235 us; speedup vs baseline: 1.0689x; 1.0404x over previous
//
#include <hip/hip_runtime.h>
#include <math.h>

#define CC 2048   // channels (C)
#define DD 256    // reduced channels (D)
#define PP 4096   // HW = 64*64
#define NB 4      // batch

typedef float f32x4 __attribute__((ext_vector_type(4)));
typedef __bf16 bfrag __attribute__((ext_vector_type(8)));

#define AS1(p) ((const __attribute__((address_space(1))) void*)(p))
#define AS3(p) ((__attribute__((address_space(3))) void*)(p))

__device__ __forceinline__ unsigned short f2bf(float f) {
    unsigned int u = __float_as_uint(f);
    u = (u + 0x7fffu + ((u >> 16) & 1u)) >> 16;
    return (unsigned short)u;
}

// ---------------- fused: x transpose+cvt (z<NB) and w3 cvt (z==NB) ----------------
__global__ __launch_bounds__(256) void prep(const float* __restrict__ x, unsigned short* __restrict__ xT,
                                            const float* __restrict__ w3, unsigned short* __restrict__ w3b) {
    const int t = threadIdx.x;
    if (blockIdx.z == NB) {
        int bid = blockIdx.y * 64 + blockIdx.x;   // 0..2047
        int base = (bid * 256 + t) * 8;
#pragma unroll
        for (int j = 0; j < 2; ++j) {
            float4 v = *(const float4*)(w3 + base + j * 4);
            ushort4 r;
            r.x = f2bf(v.x); r.y = f2bf(v.y); r.z = f2bf(v.z); r.w = f2bf(v.w);
            *(ushort4*)(w3b + base + j * 4) = r;
        }
        return;
    }
    __shared__ float tile[64 * 64];
    const int n  = blockIdx.z;
    const int c0 = blockIdx.y * 64;
    const int p0 = blockIdx.x * 64;
    const float* xn = x + (size_t)n * CC * PP;
    {
        const int cl = t >> 4;
        const int g  = t & 15;
        const int pl = g * 4;
#pragma unroll
        for (int ps = 0; ps < 4; ++ps) {
            const int c = cl + ps * 16;
            float4 v = *(const float4*)(xn + (size_t)(c0 + c) * PP + p0 + pl);
            const int gs = g ^ (c >> 2);
            *(float4*)(tile + c * 64 + gs * 4) = v;
        }
    }
    __syncthreads();
    unsigned short* xTn = xT + (size_t)n * PP * CC;
    {
        const int pl2 = t >> 4;
        const int cq  = t & 15;
        const int c4  = cq * 4;
#pragma unroll
        for (int ps = 0; ps < 4; ++ps) {
            const int p  = pl2 + ps * 16;
            const int gs2 = (p >> 2) ^ cq;
            const int base = gs2 * 4 + (p & 3);
            ushort4 r;
            r.x = f2bf(tile[(c4 + 0) * 64 + base]);
            r.y = f2bf(tile[(c4 + 1) * 64 + base]);
            r.z = f2bf(tile[(c4 + 2) * 64 + base]);
            r.w = f2bf(tile[(c4 + 3) * 64 + base]);
            *(ushort4*)(xTn + (size_t)(p0 + p) * CC + c0 + c4) = r;
        }
    }
}

// ---------------- assembly = relu(w3 . x + b3) ----------------
// m201-faithful 4-phase template: 256x256 tile, BK=64, 8 waves (2M x 4N),
// wave tile 128x64 via 8x4 of mfma_f32_16x16x32_bf16. Per K-tile, 4 phases
// of {phase's ds_reads (12/4/8/0) + 1 half-tile global_load_lds ->
// [lgkm(8) if 12 reads] -> barrier -> lgkm(0)+sched_barrier -> setprio(1)
// -> 16 MFMA (one C-quadrant x K=64) -> setprio(0) -> barrier}. Counted
// vmcnt(4) once per tile at phase 4 (never 0 in main loop). 16x16 frags
// read only 16 rows per chunk-group, so the 3-bit XOR (chunk ^= row&7)
// reaches the free 2-way conflict level (32x32 frags are stuck at 4-way).
// Stage slots: p1/p2 = A(kt+1) (other buffer, safe after prev tile's final
// barrier); p3/p4 = B(kt+2) (same buffer; B(kt) reads all retired by p2's
// lgkm(0) + barrier). Steady-state in flight at tile end = B(kt+2)'s 4 ops.
// NO XCD swizzle (round-1 evidence: natural order keeps B L2-resident,
// FETCH 99 MB vs 270 MB swizzled).
__global__ __launch_bounds__(512, 2) void gemm_assembly(
    const unsigned short* __restrict__ w3b,
    const unsigned short* __restrict__ xT,
    const float* __restrict__ b3,
    float* __restrict__ out)
{
    // layout (bytes): A: buf*32768 + half*16384 + row*128 ; B: +65536 same
    __shared__ __align__(16) char sm[131072];

    const int t    = threadIdx.x;
    const int wave = t >> 6;
    const int lane = t & 63;
    const int swz  = lane & 7;

    const int p0 = blockIdx.x << 8;
    const int m0 = blockIdx.y << 8;
    const int nb = blockIdx.z;

    // staging: thread t covers row rA (+64 for 2nd issue), global chunk g.
    // phys slot s of row r holds global k-chunk s^(r&7) (XOR on the GLOBAL
    // address so the wave-uniform-base LDS layout stays linear).
    const int rA = t >> 3;              // 0..63
    const int g  = (t & 7) ^ (rA & 7);
    const unsigned short* Ag = w3b + (size_t)(m0 + rA) * CC + g * 8;
    const unsigned short* Bg = xT + (size_t)nb * PP * CC + (size_t)(p0 + rA) * CC + g * 8;
    const int ldsw = wave << 10;        // wave*1024 (HW adds lane*16)

    // ds_read bases: wave's A half = wave>>2 ; B half = (wave&3)>>1,
    // B sub-offset (wave&1)*64 rows. Row within a 16-row frag = lane&15.
    const char* Abase = sm + ((wave >> 2) << 14) + (lane & 15) * 128;
    const char* Bbase = sm + 65536 + (((wave & 3) >> 1) << 14) + ((wave & 1) << 13) + (lane & 15) * 128;

    // 16x16x32 frag: lane reads k-chunk (ks*4 + lane>>4), phys = logical ^ (row&7);
    // row&7 == lane&7 for all frags. ck1 = ck0 ^ 0x40.
    const int ck0 = (((lane >> 4) ^ swz) << 4);
    const int ck1 = ck0 ^ 0x40;

    f32x4 acc[8][4];
#pragma unroll
    for (int i = 0; i < 8; ++i)
#pragma unroll
        for (int j = 0; j < 4; ++j)
            acc[i][j] = (f32x4){0.f, 0.f, 0.f, 0.f};

    bfrag a0k0, a0k1, a1k0, a1k1, a2k0, a2k1, a3k0, a3k1;   // A mi-group (4 x 2ks)
    bfrag bA0k0, bA0k1, bA1k0, bA1k1;                       // B ni0-1
    bfrag bB0k0, bB0k1, bB1k0, bB1k1;                       // B ni2-3

#define STG(SB, DO, kt, h) do { \
    const unsigned short* _s = (SB) + (size_t)(h) * 128 * CC + (size_t)(kt) * 64; \
    char* _d = sm + (DO) + (((kt) & 1) << 15) + ((h) << 14) + ldsw; \
    __builtin_amdgcn_global_load_lds(AS1(_s), AS3(_d), 16, 0, 0); \
    __builtin_amdgcn_global_load_lds(AS1(_s + 64 * CC), AS3(_d + 8192), 16, 0, 0); \
} while (0)

#define LD(dst, BASE, OFF) dst = *(const bfrag*)((BASE) + (OFF))
#define Q(I, J, A_, B_) acc[I][J] = __builtin_amdgcn_mfma_f32_16x16x32_bf16(A_, B_, acc[I][J], 0, 0, 0)
#define BARR __builtin_amdgcn_s_barrier()
#define SB0  __builtin_amdgcn_sched_barrier(0)
#define LG0 do { asm volatile("s_waitcnt lgkmcnt(0)" ::: "memory"); __builtin_amdgcn_sched_barrier(0); } while (0)
#define PRI(x) __builtin_amdgcn_s_setprio(x)

#define TILE(P, kt, IA, IB, VM4, VM0) do { \
    SB0; \
    /* phase 1: (mh0,nh0) — A mi0-3 + B ni0-1 = 12 reads; stage A(kt+1)h0 */ \
    LD(a0k0, Abase, ((P) << 15) + (0 << 11) + ck0); LD(a0k1, Abase, ((P) << 15) + (0 << 11) + ck1); \
    LD(a1k0, Abase, ((P) << 15) + (1 << 11) + ck0); LD(a1k1, Abase, ((P) << 15) + (1 << 11) + ck1); \
    LD(a2k0, Abase, ((P) << 15) + (2 << 11) + ck0); LD(a2k1, Abase, ((P) << 15) + (2 << 11) + ck1); \
    LD(a3k0, Abase, ((P) << 15) + (3 << 11) + ck0); LD(a3k1, Abase, ((P) << 15) + (3 << 11) + ck1); \
    LD(bA0k0, Bbase, ((P) << 15) + (0 << 11) + ck0); LD(bA0k1, Bbase, ((P) << 15) + (0 << 11) + ck1); \
    LD(bA1k0, Bbase, ((P) << 15) + (1 << 11) + ck0); LD(bA1k1, Bbase, ((P) << 15) + (1 << 11) + ck1); \
    if (IA) STG(Ag, 0, (kt) + 1, 0); \
    SB0; \
    asm volatile("s_waitcnt lgkmcnt(8)" ::: "memory"); \
    BARR; LG0; PRI(1); \
    Q(0, 0, a0k0, bA0k0); Q(1, 0, a1k0, bA0k0); Q(2, 0, a2k0, bA0k0); Q(3, 0, a3k0, bA0k0); \
    Q(0, 1, a0k0, bA1k0); Q(1, 1, a1k0, bA1k0); Q(2, 1, a2k0, bA1k0); Q(3, 1, a3k0, bA1k0); \
    Q(0, 0, a0k1, bA0k1); Q(1, 0, a1k1, bA0k1); Q(2, 0, a2k1, bA0k1); Q(3, 0, a3k1, bA0k1); \
    Q(0, 1, a0k1, bA1k1); Q(1, 1, a1k1, bA1k1); Q(2, 1, a2k1, bA1k1); Q(3, 1, a3k1, bA1k1); \
    PRI(0); BARR; \
    /* phase 2: (mh0,nh1) — B ni2-3 = 4 reads; stage A(kt+1)h1 */ \
    LD(bB0k0, Bbase, ((P) << 15) + (2 << 11) + ck0); LD(bB0k1, Bbase, ((P) << 15) + (2 << 11) + ck1); \
    LD(bB1k0, Bbase, ((P) << 15) + (3 << 11) + ck0); LD(bB1k1, Bbase, ((P) << 15) + (3 << 11) + ck1); \
    if (IA) STG(Ag, 0, (kt) + 1, 1); \
    SB0; \
    BARR; LG0; PRI(1); \
    Q(0, 2, a0k0, bB0k0); Q(1, 2, a1k0, bB0k0); Q(2, 2, a2k0, bB0k0); Q(3, 2, a3k0, bB0k0); \
    Q(0, 3, a0k0, bB1k0); Q(1, 3, a1k0, bB1k0); Q(2, 3, a2k0, bB1k0); Q(3, 3, a3k0, bB1k0); \
    Q(0, 2, a0k1, bB0k1); Q(1, 2, a1k1, bB0k1); Q(2, 2, a2k1, bB0k1); Q(3, 2, a3k1, bB0k1); \
    Q(0, 3, a0k1, bB1k1); Q(1, 3, a1k1, bB1k1); Q(2, 3, a2k1, bB1k1); Q(3, 3, a3k1, bB1k1); \
    PRI(0); BARR; \
    /* phase 3: (mh1,nh1) — A mi4-7 = 8 reads; stage B(kt+2)h0 */ \
    LD(a0k0, Abase, ((P) << 15) + (4 << 11) + ck0); LD(a0k1, Abase, ((P) << 15) + (4 << 11) + ck1); \
    LD(a1k0, Abase, ((P) << 15) + (5 << 11) + ck0); LD(a1k1, Abase, ((P) << 15) + (5 << 11) + ck1); \
    LD(a2k0, Abase, ((P) << 15) + (6 << 11) + ck0); LD(a2k1, Abase, ((P) << 15) + (6 << 11) + ck1); \
    LD(a3k0, Abase, ((P) << 15) + (7 << 11) + ck0); LD(a3k1, Abase, ((P) << 15) + (7 << 11) + ck1); \
    if (IB) STG(Bg, 65536, (kt) + 2, 0); \
    SB0; \
    BARR; LG0; PRI(1); \
    Q(4, 2, a0k0, bB0k0); Q(5, 2, a1k0, bB0k0); Q(6, 2, a2k0, bB0k0); Q(7, 2, a3k0, bB0k0); \
    Q(4, 3, a0k0, bB1k0); Q(5, 3, a1k0, bB1k0); Q(6, 3, a2k0, bB1k0); Q(7, 3, a3k0, bB1k0); \
    Q(4, 2, a0k1, bB0k1); Q(5, 2, a1k1, bB0k1); Q(6, 2, a2k1, bB0k1); Q(7, 2, a3k1, bB0k1); \
    Q(4, 3, a0k1, bB1k1); Q(5, 3, a1k1, bB1k1); Q(6, 3, a2k1, bB1k1); Q(7, 3, a3k1, bB1k1); \
    PRI(0); BARR; \
    /* phase 4: (mh1,nh0) — all from regs; stage B(kt+2)h1; counted vmcnt */ \
    if (IB) STG(Bg, 65536, (kt) + 2, 1); \
    SB0; \
    BARR; SB0; PRI(1); \
    Q(4, 0, a0k0, bA0k0); Q(5, 0, a1k0, bA0k0); Q(6, 0, a2k0, bA0k0); Q(7, 0, a3k0, bA0k0); \
    Q(4, 1, a0k0, bA1k0); Q(5, 1, a1k0, bA1k0); Q(6, 1, a2k0, bA1k0); Q(7, 1, a3k0, bA1k0); \
    Q(4, 0, a0k1, bA0k1); Q(5, 0, a1k1, bA0k1); Q(6, 0, a2k1, bA0k1); Q(7, 0, a3k1, bA0k1); \
    Q(4, 1, a0k1, bA1k1); Q(5, 1, a1k1, bA1k1); Q(6, 1, a2k1, bA1k1); Q(7, 1, a3k1, bA1k1); \
    PRI(0); \
    if (VM4) asm volatile("s_waitcnt vmcnt(4)" ::: "memory"); \
    if (VM0) asm volatile("s_waitcnt vmcnt(0)" ::: "memory"); \
    BARR; \
} while (0)

    // prologue: A(0),B(0) -> buf0; B(1) -> buf1. vmcnt(4) retires A(0)+B(0),
    // leaves B(1)'s 4 ops = loop entry invariant (in flight = B(kt+1)).
    STG(Ag, 0, 0, 0); STG(Ag, 0, 0, 1);
    STG(Bg, 65536, 0, 0); STG(Bg, 65536, 0, 1);
    STG(Bg, 65536, 1, 0); STG(Bg, 65536, 1, 1);
    asm volatile("s_waitcnt vmcnt(4)" ::: "memory");
    BARR;

#pragma unroll 1
    for (int kt = 0; kt < 30; kt += 2) {
        TILE(0, kt,     1, 1, 1, 0);
        TILE(1, kt + 1, 1, 1, 1, 0);
    }
    TILE(0, 30, 1, 0, 0, 1);   // stages A(31) p1/p2; drains with vmcnt(0)
    TILE(1, 31, 0, 0, 0, 0);   // pure compute

#undef TILE
#undef STG
#undef LD
#undef Q
#undef BARR
#undef SB0
#undef LG0
#undef PRI

    // epilogue: 16x16 C/D layout: row = (lane>>4)*4 + reg, col = lane&15
    const int wr = (wave >> 2) << 7;
    const int wc = (wave & 3) << 6;
    const int q4 = (lane >> 4) << 2;
    const int cl = lane & 15;
    float* outn = out + (size_t)nb * CC * PP;
#pragma unroll
    for (int mi = 0; mi < 8; ++mi) {
#pragma unroll
        for (int r = 0; r < 4; ++r) {
            const int o = m0 + wr + mi * 16 + q4 + r;
            const float bias = b3[o];
            float* orow = outn + (size_t)o * PP + p0 + wc + cl;
#pragma unroll
            for (int ni = 0; ni < 4; ++ni) {
                float v = acc[mi][ni][r] + bias;
                orow[ni * 16] = v > 0.f ? v : 0.f;
            }
        }
    }
}

// ---------------- guarded attention fallback (alpha != 0 only) ----------------
__global__ void fb_e12(const float* __restrict__ x,
                       const float* __restrict__ w1, const float* __restrict__ b1,
                       const float* __restrict__ w2, const float* __restrict__ b2,
                       const float* __restrict__ alpha,
                       float* __restrict__ e1, float* __restrict__ e2) {
    if (alpha[0] == 0.f) return;
    const size_t total = (size_t)NB * DD * PP;
    for (size_t idx = (size_t)blockIdx.x * blockDim.x + threadIdx.x; idx < total;
         idx += (size_t)gridDim.x * blockDim.x) {
        int p = (int)(idx % PP);
        size_t nd = idx / PP;
        int d = (int)(nd % DD);
        int n = (int)(nd / DD);
        const float* xn = x + (size_t)n * CC * PP + p;
        float s1 = b1[d], s2 = b2[d];
        for (int c = 0; c < CC; ++c) {
            float xv = xn[(size_t)c * PP];
            s1 += w1[(size_t)d * CC + c] * xv;
            s2 += w2[(size_t)d * CC + c] * xv;
        }
        e1[idx] = fmaxf(s1, 0.f);
        e2[idx] = fmaxf(s2, 0.f);
    }
}

__global__ void fb_attn(const float* __restrict__ x,
                        const float* __restrict__ e1, const float* __restrict__ e2,
                        const float* __restrict__ alpha,
                        float* __restrict__ out) {
    const float a = alpha[0];
    if (a == 0.f) return;   // uniform early-exit (no barrier crossed)
    __shared__ float s[PP];
    __shared__ float e1i[DD];
    __shared__ float red[256];
    const int t = threadIdx.x;
    for (int ii = blockIdx.x; ii < NB * PP; ii += gridDim.x) {
        const int n = ii >> 12;
        const int i = ii & (PP - 1);
        const float* e1n = e1 + (size_t)n * DD * PP;
        const float* e2n = e2 + (size_t)n * DD * PP;
        if (t < DD) e1i[t] = e1n[(size_t)t * PP + i];
        __syncthreads();
        for (int j = t; j < PP; j += 256) {
            float acc = 0.f;
            for (int d = 0; d < DD; ++d) acc += e1i[d] * e2n[(size_t)d * PP + j];
            s[j] = acc;
        }
        __syncthreads();
        float m = -INFINITY;
        for (int j = t; j < PP; j += 256) m = fmaxf(m, s[j]);
        red[t] = m; __syncthreads();
        for (int o = 128; o > 0; o >>= 1) { if (t < o) red[t] = fmaxf(red[t], red[t + o]); __syncthreads(); }
        m = red[0]; __syncthreads();
        float l = 0.f;
        for (int j = t; j < PP; j += 256) { float e = __expf(s[j] - m); s[j] = e; l += e; }
        red[t] = l; __syncthreads();
        for (int o = 128; o > 0; o >>= 1) { if (t < o) red[t] += red[t + o]; __syncthreads(); }
        l = red[0]; __syncthreads();
        const float inv = a / l;
        const float* xn = x + (size_t)n * CC * PP;
        float* on = out + (size_t)n * CC * PP;
        for (int c = t; c < CC; c += 256) {
            const float* xr = xn + (size_t)c * PP;
            float acc = 0.f;
            for (int j = 0; j < PP; ++j) acc += s[j] * xr[j];
            on[(size_t)c * PP + i] += inv * acc;
        }
        __syncthreads();
    }
}

extern "C" void kernel_launch(void* const* d_in, const int* in_sizes, int n_in,
                              void* d_out, int out_size, void* d_ws, size_t ws_size,
                              hipStream_t stream) {
    (void)in_sizes; (void)n_in; (void)out_size; (void)ws_size;
    const float* x     = (const float*)d_in[0];
    const float* w1    = (const float*)d_in[1];
    const float* b1    = (const float*)d_in[2];
    const float* w2    = (const float*)d_in[3];
    const float* b2    = (const float*)d_in[4];
    const float* w3    = (const float*)d_in[5];
    const float* b3    = (const float*)d_in[6];
    const float* alpha = (const float*)d_in[7];
    float* out = (float*)d_out;

    unsigned short* xT  = (unsigned short*)d_ws;
    unsigned short* w3b = (unsigned short*)((char*)d_ws + (size_t)NB * PP * CC * 2);
    float* e1 = (float*)d_ws;
    float* e2 = e1 + (size_t)NB * DD * PP;

    prep<<<dim3(PP / 64, CC / 64, NB + 1), dim3(256), 0, stream>>>(x, xT, w3, w3b);
    gemm_assembly<<<dim3(PP / 256, CC / 256, NB), dim3(512), 0, stream>>>(w3b, xT, b3, out);
    fb_e12<<<dim3(512), dim3(256), 0, stream>>>(x, w1, b1, w2, b2, alpha, e1, e2);
    fb_attn<<<dim3(1024), dim3(256), 0, stream>>>(x, e1, e2, alpha, out);
}

// Round 4
// 360.020 us; speedup vs baseline: 1.0725x; 1.0034x over previous
//
#include <hip/hip_runtime.h>
#include <math.h>

#define CC 2048   // channels (C)
#define DD 256    // reduced channels (D)
#define PP 4096   // HW = 64*64
#define NB 4      // batch

typedef float f32x4 __attribute__((ext_vector_type(4)));
typedef __bf16 bfrag __attribute__((ext_vector_type(8)));

#define AS1(p) ((const __attribute__((address_space(1))) void*)(p))
#define AS3(p) ((__attribute__((address_space(3))) void*)(p))

__device__ __forceinline__ unsigned short f2bf(float f) {
    unsigned int u = __float_as_uint(f);
    u = (u + 0x7fffu + ((u >> 16) & 1u)) >> 16;
    return (unsigned short)u;
}

// ---------------- fused: x transpose+cvt (z<NB) and w3 cvt (z==NB) ----------------
__global__ __launch_bounds__(256) void prep(const float* __restrict__ x, unsigned short* __restrict__ xT,
                                            const float* __restrict__ w3, unsigned short* __restrict__ w3b) {
    const int t = threadIdx.x;
    if (blockIdx.z == NB) {
        int bid = blockIdx.y * 64 + blockIdx.x;   // 0..2047
        int base = (bid * 256 + t) * 8;
#pragma unroll
        for (int j = 0; j < 2; ++j) {
            float4 v = *(const float4*)(w3 + base + j * 4);
            ushort4 r;
            r.x = f2bf(v.x); r.y = f2bf(v.y); r.z = f2bf(v.z); r.w = f2bf(v.w);
            *(ushort4*)(w3b + base + j * 4) = r;
        }
        return;
    }
    __shared__ float tile[64 * 64];
    const int n  = blockIdx.z;
    const int c0 = blockIdx.y * 64;
    const int p0 = blockIdx.x * 64;
    const float* xn = x + (size_t)n * CC * PP;
    {
        const int cl = t >> 4;
        const int g  = t & 15;
        const int pl = g * 4;
#pragma unroll
        for (int ps = 0; ps < 4; ++ps) {
            const int c = cl + ps * 16;
            float4 v = *(const float4*)(xn + (size_t)(c0 + c) * PP + p0 + pl);
            const int gs = g ^ (c >> 2);
            *(float4*)(tile + c * 64 + gs * 4) = v;
        }
    }
    __syncthreads();
    unsigned short* xTn = xT + (size_t)n * PP * CC;
    {
        const int pl2 = t >> 4;
        const int cq  = t & 15;
        const int c4  = cq * 4;
#pragma unroll
        for (int ps = 0; ps < 4; ++ps) {
            const int p  = pl2 + ps * 16;
            const int gs2 = (p >> 2) ^ cq;
            const int base = gs2 * 4 + (p & 3);
            ushort4 r;
            r.x = f2bf(tile[(c4 + 0) * 64 + base]);
            r.y = f2bf(tile[(c4 + 1) * 64 + base]);
            r.z = f2bf(tile[(c4 + 2) * 64 + base]);
            r.w = f2bf(tile[(c4 + 3) * 64 + base]);
            *(ushort4*)(xTn + (size_t)(p0 + p) * CC + c0 + c4) = r;
        }
    }
}

// ---------------- assembly = relu(w3 . x + b3) ----------------
// 256x256 tile, BK=64, 8 waves (2M x 4N), wave tile 128x64 via 8x4 of
// mfma_f32_16x16x32_bf16, conflict-free chunk-XOR LDS (round-3, verified 0
// bank conflicts). Round-4 change: software-pipelined phases — each ds_read
// group is issued ONE PHASE BEFORE its consuming MFMA cluster and gated by a
// counted lgkmcnt (4/8/8), so the LDS pipe serves the next cluster's reads
// WHILE the current cluster's MFMAs run (round-3 measured per-tile = MFMA
// 2480cyc + LDS 2300cyc = 4820 = exact serial sum; this overlaps them).
//   p1: issue R2 (B ni23 -> S2) ; stage A(kt+1)h0 ; WLG(4) -> Q1 (a0-3 x S1)
//   p2: issue R3 (A mi4-7 -> a4-7) ; stage A(kt+1)h1 ; WLG(8) -> Q2 (a0-3 x S2)
//   p3: BARR ; stage B(kt+2)h0 ; vmcnt(2) ; BARR(handoff) ;
//       issue R1'A (next A mi0-3 -> a0-3, dead after Q2) ; WLG(8) -> Q3 (a4-7 x S2)
//   p4: stage B(kt+2)h1 ; issue R1'B (next B ni01 -> S2, dead after Q3) ; Q4 (a4-7 x S1)
// B register sets swap roles every tile (S1 holds ni01, S2 ni23) so B stays
// at 8 frags; A doubles to 16 frags (mi4-7 separate) to break the R3/Q2 WAR.
// 4 barriers/tile (was 8). vmcnt(2) keeps B(kt+2)h0 in flight (never 0 in
// main loop). NO XCD swizzle (round-1: natural order keeps B L2-resident).
__global__ __launch_bounds__(512, 2) void gemm_assembly(
    const unsigned short* __restrict__ w3b,
    const unsigned short* __restrict__ xT,
    const float* __restrict__ b3,
    float* __restrict__ out)
{
    // layout (bytes): A: buf*32768 + half*16384 + row*128 ; B: +65536 same
    __shared__ __align__(16) char sm[131072];

    const int t    = threadIdx.x;
    const int wave = t >> 6;
    const int lane = t & 63;
    const int swz  = lane & 7;

    const int p0 = blockIdx.x << 8;
    const int m0 = blockIdx.y << 8;
    const int nb = blockIdx.z;

    // staging: thread t covers row rA (+64 for 2nd issue), global chunk g.
    // phys slot s of row r holds global k-chunk s^(r&7) (XOR on the GLOBAL
    // address so the wave-uniform-base LDS layout stays linear).
    const int rA = t >> 3;              // 0..63
    const int g  = (t & 7) ^ (rA & 7);
    const unsigned short* Ag = w3b + (size_t)(m0 + rA) * CC + g * 8;
    const unsigned short* Bg = xT + (size_t)nb * PP * CC + (size_t)(p0 + rA) * CC + g * 8;
    const int ldsw = wave << 10;        // wave*1024 (HW adds lane*16)

    // ds_read bases: wave's A half = wave>>2 ; B half = (wave&3)>>1,
    // B sub-offset (wave&1)*64 rows. Row within a 16-row frag = lane&15.
    const char* Abase = sm + ((wave >> 2) << 14) + (lane & 15) * 128;
    const char* Bbase = sm + 65536 + (((wave & 3) >> 1) << 14) + ((wave & 1) << 13) + (lane & 15) * 128;

    // 16x16x32 frag: lane reads k-chunk (ks*4 + lane>>4), phys = logical ^ (row&7);
    // row&7 == lane&7 for all frags. ck1 = ck0 ^ 0x40.
    const int ck0 = (((lane >> 4) ^ swz) << 4);
    const int ck1 = ck0 ^ 0x40;

    f32x4 acc[8][4];
#pragma unroll
    for (int i = 0; i < 8; ++i)
#pragma unroll
        for (int j = 0; j < 4; ++j)
            acc[i][j] = (f32x4){0.f, 0.f, 0.f, 0.f};

    bfrag a0k0, a0k1, a1k0, a1k1, a2k0, a2k1, a3k0, a3k1;   // A mi0-3 (repipelined each tile)
    bfrag a4k0, a4k1, a5k0, a5k1, a6k0, a6k1, a7k0, a7k1;   // A mi4-7
    bfrag bP0, bP1, bP2, bP3;                               // B set P (ni0k0,ni0k1,ni1k0,ni1k1 role-swapped)
    bfrag bQ0, bQ1, bQ2, bQ3;                               // B set Q

#define STG(SB, DO, kt, h) do { \
    const unsigned short* _s = (SB) + (size_t)(h) * 128 * CC + (size_t)(kt) * 64; \
    char* _d = sm + (DO) + (((kt) & 1) << 15) + ((h) << 14) + ldsw; \
    __builtin_amdgcn_global_load_lds(AS1(_s), AS3(_d), 16, 0, 0); \
    __builtin_amdgcn_global_load_lds(AS1(_s + 64 * CC), AS3(_d + 8192), 16, 0, 0); \
} while (0)

#define LD(dst, BASE, OFF) dst = *(const bfrag*)((BASE) + (OFF))
#define Q(I, J, A_, B_) acc[I][J] = __builtin_amdgcn_mfma_f32_16x16x32_bf16(A_, B_, acc[I][J], 0, 0, 0)
#define BARR __builtin_amdgcn_s_barrier()
#define SB0  __builtin_amdgcn_sched_barrier(0)
#define WLG(N) do { asm volatile("s_waitcnt lgkmcnt(" #N ")" ::: "memory"); __builtin_amdgcn_sched_barrier(0); } while (0)
#define WVM(N) asm volatile("s_waitcnt vmcnt(" #N ")" ::: "memory")
#define PRI(x) __builtin_amdgcn_s_setprio(x)

// Entry invariant (tile kt, buffer P): S1 holds ni01(kt), a0-3 hold mi0-3(kt)
// (both issued during tile kt-1 p3/p4, possibly still in flight); vm
// outstanding = B(kt+1)'s 4 ops. All buf-P staging retired.
#define TILE(P, NP, kt, IA, IB, IR, V2, V0, G3, S10,S11,S12,S13, S20,S21,S22,S23) do { \
    /* p1: guard barrier for STG-A (prev tile's buf-NP A reads all retired) */ \
    BARR; SB0; \
    LD(S20, Bbase, ((P) << 15) + (2 << 11) + ck0); LD(S21, Bbase, ((P) << 15) + (2 << 11) + ck1); \
    LD(S22, Bbase, ((P) << 15) + (3 << 11) + ck0); LD(S23, Bbase, ((P) << 15) + (3 << 11) + ck1); \
    if (IA) STG(Ag, 0, (kt) + 1, 0); \
    SB0; WLG(4); PRI(1); \
    Q(0, 0, a0k0, S10); Q(1, 0, a1k0, S10); Q(2, 0, a2k0, S10); Q(3, 0, a3k0, S10); \
    Q(0, 1, a0k0, S12); Q(1, 1, a1k0, S12); Q(2, 1, a2k0, S12); Q(3, 1, a3k0, S12); \
    Q(0, 0, a0k1, S11); Q(1, 0, a1k1, S11); Q(2, 0, a2k1, S11); Q(3, 0, a3k1, S11); \
    Q(0, 1, a0k1, S13); Q(1, 1, a1k1, S13); Q(2, 1, a2k1, S13); Q(3, 1, a3k1, S13); \
    PRI(0); \
    /* p2 */ \
    BARR; SB0; \
    LD(a4k0, Abase, ((P) << 15) + (4 << 11) + ck0); LD(a4k1, Abase, ((P) << 15) + (4 << 11) + ck1); \
    LD(a5k0, Abase, ((P) << 15) + (5 << 11) + ck0); LD(a5k1, Abase, ((P) << 15) + (5 << 11) + ck1); \
    LD(a6k0, Abase, ((P) << 15) + (6 << 11) + ck0); LD(a6k1, Abase, ((P) << 15) + (6 << 11) + ck1); \
    LD(a7k0, Abase, ((P) << 15) + (7 << 11) + ck0); LD(a7k1, Abase, ((P) << 15) + (7 << 11) + ck1); \
    if (IA) STG(Ag, 0, (kt) + 1, 1); \
    SB0; WLG(8); PRI(1); \
    Q(0, 2, a0k0, S20); Q(1, 2, a1k0, S20); Q(2, 2, a2k0, S20); Q(3, 2, a3k0, S20); \
    Q(0, 3, a0k0, S22); Q(1, 3, a1k0, S22); Q(2, 3, a2k0, S22); Q(3, 3, a3k0, S22); \
    Q(0, 2, a0k1, S21); Q(1, 2, a1k1, S21); Q(2, 2, a2k1, S21); Q(3, 2, a3k1, S21); \
    Q(0, 3, a0k1, S23); Q(1, 3, a1k1, S23); Q(2, 3, a2k1, S23); Q(3, 3, a3k1, S23); \
    PRI(0); \
    /* p3: entry barrier (all waves' buf-P B reads retired) -> STG Bh0 -> */ \
    /* counted vmcnt -> handoff barrier -> next-tile A reads -> Q3 */ \
    BARR; SB0; \
    if (IB) STG(Bg, 65536, (kt) + 2, 0); \
    if (V2) WVM(2); \
    if (V0) WVM(0); \
    BARR; SB0; \
    if (IR) { \
        LD(a0k0, Abase, ((NP) << 15) + (0 << 11) + ck0); LD(a0k1, Abase, ((NP) << 15) + (0 << 11) + ck1); \
        LD(a1k0, Abase, ((NP) << 15) + (1 << 11) + ck0); LD(a1k1, Abase, ((NP) << 15) + (1 << 11) + ck1); \
        LD(a2k0, Abase, ((NP) << 15) + (2 << 11) + ck0); LD(a2k1, Abase, ((NP) << 15) + (2 << 11) + ck1); \
        LD(a3k0, Abase, ((NP) << 15) + (3 << 11) + ck0); LD(a3k1, Abase, ((NP) << 15) + (3 << 11) + ck1); \
    } \
    SB0; WLG(G3); PRI(1); \
    Q(4, 2, a4k0, S20); Q(5, 2, a5k0, S20); Q(6, 2, a6k0, S20); Q(7, 2, a7k0, S20); \
    Q(4, 3, a4k0, S22); Q(5, 3, a5k0, S22); Q(6, 3, a6k0, S22); Q(7, 3, a7k0, S22); \
    Q(4, 2, a4k1, S21); Q(5, 2, a5k1, S21); Q(6, 2, a6k1, S21); Q(7, 2, a7k1, S21); \
    Q(4, 3, a4k1, S23); Q(5, 3, a5k1, S23); Q(6, 3, a6k1, S23); Q(7, 3, a7k1, S23); \
    PRI(0); \
    /* p4: stage B(kt+2)h1 ; next-tile B ni01 -> S2 (dead after Q3) ; Q4 */ \
    if (IB) STG(Bg, 65536, (kt) + 2, 1); \
    if (IR) { \
        LD(S20, Bbase, ((NP) << 15) + (0 << 11) + ck0); LD(S21, Bbase, ((NP) << 15) + (0 << 11) + ck1); \
        LD(S22, Bbase, ((NP) << 15) + (1 << 11) + ck0); LD(S23, Bbase, ((NP) << 15) + (1 << 11) + ck1); \
    } \
    SB0; PRI(1); \
    Q(4, 0, a4k0, S10); Q(5, 0, a5k0, S10); Q(6, 0, a6k0, S10); Q(7, 0, a7k0, S10); \
    Q(4, 1, a4k0, S12); Q(5, 1, a5k0, S12); Q(6, 1, a6k0, S12); Q(7, 1, a7k0, S12); \
    Q(4, 0, a4k1, S11); Q(5, 0, a5k1, S11); Q(6, 0, a6k1, S11); Q(7, 0, a7k1, S11); \
    Q(4, 1, a4k1, S13); Q(5, 1, a5k1, S13); Q(6, 1, a6k1, S13); Q(7, 1, a7k1, S13); \
    PRI(0); \
} while (0)

    // prologue: A(0),B(0) -> buf0; B(1) -> buf1. vmcnt(4) retires A(0)+B(0),
    // leaves B(1)'s 4 ops. Then issue tile0's R1 (A mi0-3 + B ni01 -> bP).
    STG(Ag, 0, 0, 0); STG(Ag, 0, 0, 1);
    STG(Bg, 65536, 0, 0); STG(Bg, 65536, 0, 1);
    STG(Bg, 65536, 1, 0); STG(Bg, 65536, 1, 1);
    WVM(4);
    BARR; SB0;
    LD(a0k0, Abase, (0 << 11) + ck0); LD(a0k1, Abase, (0 << 11) + ck1);
    LD(a1k0, Abase, (1 << 11) + ck0); LD(a1k1, Abase, (1 << 11) + ck1);
    LD(a2k0, Abase, (2 << 11) + ck0); LD(a2k1, Abase, (2 << 11) + ck1);
    LD(a3k0, Abase, (3 << 11) + ck0); LD(a3k1, Abase, (3 << 11) + ck1);
    LD(bP0, Bbase, (0 << 11) + ck0); LD(bP1, Bbase, (0 << 11) + ck1);
    LD(bP2, Bbase, (1 << 11) + ck0); LD(bP3, Bbase, (1 << 11) + ck1);
    SB0;

#pragma unroll 1
    for (int kt = 0; kt < 30; kt += 2) {
        TILE(0, 1, kt,     1, 1, 1, 1, 0, 8, bP0, bP1, bP2, bP3, bQ0, bQ1, bQ2, bQ3);
        TILE(1, 0, kt + 1, 1, 1, 1, 1, 0, 8, bQ0, bQ1, bQ2, bQ3, bP0, bP1, bP2, bP3);
    }
    // tile 30: stages A(31); no B(32); drains all staging (vmcnt 0) before
    // tile31's reads. tile 31: pure compute, no next-tile prefetch.
    TILE(0, 1, 30, 1, 0, 1, 0, 1, 8, bP0, bP1, bP2, bP3, bQ0, bQ1, bQ2, bQ3);
    TILE(1, 0, 31, 0, 0, 0, 0, 0, 0, bQ0, bQ1, bQ2, bQ3, bP0, bP1, bP2, bP3);

#undef TILE
#undef STG
#undef LD
#undef Q
#undef BARR
#undef SB0
#undef WLG
#undef WVM
#undef PRI

    // epilogue: 16x16 C/D layout: row = (lane>>4)*4 + reg, col = lane&15
    const int wr = (wave >> 2) << 7;
    const int wc = (wave & 3) << 6;
    const int q4 = (lane >> 4) << 2;
    const int cl = lane & 15;
    float* outn = out + (size_t)nb * CC * PP;
#pragma unroll
    for (int mi = 0; mi < 8; ++mi) {
#pragma unroll
        for (int r = 0; r < 4; ++r) {
            const int o = m0 + wr + mi * 16 + q4 + r;
            const float bias = b3[o];
            float* orow = outn + (size_t)o * PP + p0 + wc + cl;
#pragma unroll
            for (int ni = 0; ni < 4; ++ni) {
                float v = acc[mi][ni][r] + bias;
                orow[ni * 16] = v > 0.f ? v : 0.f;
            }
        }
    }
}

// ---------------- guarded attention fallback (alpha != 0 only) ----------------
__global__ void fb_e12(const float* __restrict__ x,
                       const float* __restrict__ w1, const float* __restrict__ b1,
                       const float* __restrict__ w2, const float* __restrict__ b2,
                       const float* __restrict__ alpha,
                       float* __restrict__ e1, float* __restrict__ e2) {
    if (alpha[0] == 0.f) return;
    const size_t total = (size_t)NB * DD * PP;
    for (size_t idx = (size_t)blockIdx.x * blockDim.x + threadIdx.x; idx < total;
         idx += (size_t)gridDim.x * blockDim.x) {
        int p = (int)(idx % PP);
        size_t nd = idx / PP;
        int d = (int)(nd % DD);
        int n = (int)(nd / DD);
        const float* xn = x + (size_t)n * CC * PP + p;
        float s1 = b1[d], s2 = b2[d];
        for (int c = 0; c < CC; ++c) {
            float xv = xn[(size_t)c * PP];
            s1 += w1[(size_t)d * CC + c] * xv;
            s2 += w2[(size_t)d * CC + c] * xv;
        }
        e1[idx] = fmaxf(s1, 0.f);
        e2[idx] = fmaxf(s2, 0.f);
    }
}

__global__ void fb_attn(const float* __restrict__ x,
                        const float* __restrict__ e1, const float* __restrict__ e2,
                        const float* __restrict__ alpha,
                        float* __restrict__ out) {
    const float a = alpha[0];
    if (a == 0.f) return;   // uniform early-exit (no barrier crossed)
    __shared__ float s[PP];
    __shared__ float e1i[DD];
    __shared__ float red[256];
    const int t = threadIdx.x;
    for (int ii = blockIdx.x; ii < NB * PP; ii += gridDim.x) {
        const int n = ii >> 12;
        const int i = ii & (PP - 1);
        const float* e1n = e1 + (size_t)n * DD * PP;
        const float* e2n = e2 + (size_t)n * DD * PP;
        if (t < DD) e1i[t] = e1n[(size_t)t * PP + i];
        __syncthreads();
        for (int j = t; j < PP; j += 256) {
            float acc = 0.f;
            for (int d = 0; d < DD; ++d) acc += e1i[d] * e2n[(size_t)d * PP + j];
            s[j] = acc;
        }
        __syncthreads();
        float m = -INFINITY;
        for (int j = t; j < PP; j += 256) m = fmaxf(m, s[j]);
        red[t] = m; __syncthreads();
        for (int o = 128; o > 0; o >>= 1) { if (t < o) red[t] = fmaxf(red[t], red[t + o]); __syncthreads(); }
        m = red[0]; __syncthreads();
        float l = 0.f;
        for (int j = t; j < PP; j += 256) { float e = __expf(s[j] - m); s[j] = e; l += e; }
        red[t] = l; __syncthreads();
        for (int o = 128; o > 0; o >>= 1) { if (t < o) red[t] += red[t + o]; __syncthreads(); }
        l = red[0]; __syncthreads();
        const float inv = a / l;
        const float* xn = x + (size_t)n * CC * PP;
        float* on = out + (size_t)n * CC * PP;
        for (int c = t; c < CC; c += 256) {
            const float* xr = xn + (size_t)c * PP;
            float acc = 0.f;
            for (int j = 0; j < PP; ++j) acc += s[j] * xr[j];
            on[(size_t)c * PP + i] += inv * acc;
        }
        __syncthreads();
    }
}

extern "C" void kernel_launch(void* const* d_in, const int* in_sizes, int n_in,
                              void* d_out, int out_size, void* d_ws, size_t ws_size,
                              hipStream_t stream) {
    (void)in_sizes; (void)n_in; (void)out_size; (void)ws_size;
    const float* x     = (const float*)d_in[0];
    const float* w1    = (const float*)d_in[1];
    const float* b1    = (const float*)d_in[2];
    const float* w2    = (const float*)d_in[3];
    const float* b2    = (const float*)d_in[4];
    const float* w3    = (const float*)d_in[5];
    const float* b3    = (const float*)d_in[6];
    const float* alpha = (const float*)d_in[7];
    float* out = (float*)d_out;

    unsigned short* xT  = (unsigned short*)d_ws;
    unsigned short* w3b = (unsigned short*)((char*)d_ws + (size_t)NB * PP * CC * 2);
    float* e1 = (float*)d_ws;
    float* e2 = e1 + (size_t)NB * DD * PP;

    prep<<<dim3(PP / 64, CC / 64, NB + 1), dim3(256), 0, stream>>>(x, xT, w3, w3b);
    gemm_assembly<<<dim3(PP / 256, CC / 256, NB), dim3(512), 0, stream>>>(w3b, xT, b3, out);
    fb_e12<<<dim3(512), dim3(256), 0, stream>>>(x, w1, b1, w2, b2, alpha, e1, e2);
    fb_attn<<<dim3(1024), dim3(256), 0, stream>>>(x, e1, e2, alpha, out);
}